// Round 9
// baseline (465.146 us; speedup 1.0000x reference)
//
#include <hip/hip_runtime.h>
#include <hip/hip_bf16.h>
#include <math.h>

#define BB   2
#define SS   1024
#define HIDD 768
#define NHH  12
#define HDD  64

typedef float f32x4 __attribute__((ext_vector_type(4)));
typedef short bf8   __attribute__((ext_vector_type(8)));   // 8 bf16 (bit pattern)
typedef unsigned short u16;
typedef unsigned int u32;
typedef u16 u16x8 __attribute__((ext_vector_type(8)));
typedef u16 u16x4 __attribute__((ext_vector_type(4)));

__device__ __forceinline__ u16 f2bf(float x) {  // RNE f32->bf16
  unsigned int u = __float_as_uint(x);
  u += 0x7fffu + ((u >> 16) & 1u);
  return (u16)(u >> 16);
}
__device__ __forceinline__ float bf2f(u16 x) {
  return __uint_as_float(((u32)x) << 16);
}

__device__ __forceinline__ bf8 ldfrag(const u16* t, int row, int kc) {
  return *(const bf8*)&t[row * 64 + (kc ^ ((row & 7) << 3))];
}

// ---------------------------------------------------------------------------
// Prep kernels (unchanged).
// ---------------------------------------------------------------------------
__global__ __launch_bounds__(256) void xconv_kernel(const float* __restrict__ X,
                                                    u16* __restrict__ Xb) {
  int i = (blockIdx.x * 256 + threadIdx.x) * 8;
  float4 a = *(const float4*)&X[i];
  float4 b = *(const float4*)&X[i + 4];
  u16x8 o;
  o[0] = f2bf(a.x); o[1] = f2bf(a.y); o[2] = f2bf(a.z); o[3] = f2bf(a.w);
  o[4] = f2bf(b.x); o[5] = f2bf(b.y); o[6] = f2bf(b.z); o[7] = f2bf(b.w);
  *(u16x8*)&Xb[i] = o;
}

__global__ __launch_bounds__(256) void wtconv_kernel(
    const float* __restrict__ Wq, const float* __restrict__ Wk,
    const float* __restrict__ Wv, u16* __restrict__ Wt) {
  const int zi = blockIdx.z;
  const float* __restrict__ W = (zi == 0) ? Wq : (zi == 1 ? Wk : Wv);
  const int n0 = blockIdx.x * 64;
  const int k0 = blockIdx.y * 64;
  __shared__ float t[64][65];
  const int tid = threadIdx.x;
  {
    const int kl = tid >> 4;
    const int nl = (tid & 15) * 4;
#pragma unroll
    for (int p = 0; p < 4; ++p) {
      float4 v = *(const float4*)&W[(size_t)(k0 + kl + 16 * p) * HIDD + n0 + nl];
      t[kl + 16 * p][nl + 0] = v.x;
      t[kl + 16 * p][nl + 1] = v.y;
      t[kl + 16 * p][nl + 2] = v.z;
      t[kl + 16 * p][nl + 3] = v.w;
    }
  }
  __syncthreads();
  {
    const int nl = tid >> 4;
    const int cl = (tid & 15) * 4;
#pragma unroll
    for (int p = 0; p < 4; ++p) {
      const int n = nl + 16 * p;
      u16x4 o;
      o[0] = f2bf(t[cl + 0][n]);
      o[1] = f2bf(t[cl + 1][n]);
      o[2] = f2bf(t[cl + 2][n]);
      o[3] = f2bf(t[cl + 3][n]);
      *(u16x4*)&Wt[(size_t)(zi * HIDD + n0 + n) * HIDD + k0 + cl] = o;
    }
  }
}

__global__ __launch_bounds__(256) void econv_kernel(const float* __restrict__ demb,
                                                    u16* __restrict__ eb) {
  int i = (blockIdx.x * 256 + threadIdx.x) * 8;
  if (i < 2047 * HDD) {
    float4 a = *(const float4*)&demb[i];
    float4 b = *(const float4*)&demb[i + 4];
    u16x8 o;
    o[0] = f2bf(a.x); o[1] = f2bf(a.y); o[2] = f2bf(a.z); o[3] = f2bf(a.w);
    o[4] = f2bf(b.x); o[5] = f2bf(b.y); o[6] = f2bf(b.z); o[7] = f2bf(b.w);
    *(u16x8*)&eb[i] = o;
  }
}

__global__ __launch_bounds__(256) void sconv_kernel(const float* __restrict__ sm,
                                                    u16* __restrict__ smb) {
  int i = (blockIdx.x * 256 + threadIdx.x) * 8;
  float4 a = *(const float4*)&sm[i];
  float4 b = *(const float4*)&sm[i + 4];
  u16x8 o;
  o[0] = f2bf(a.x); o[1] = f2bf(a.y); o[2] = f2bf(a.z); o[3] = f2bf(a.w);
  o[4] = f2bf(b.x); o[5] = f2bf(b.y); o[6] = f2bf(b.z); o[7] = f2bf(b.w);
  *(u16x8*)&smb[i] = o;
}

// ---------------------------------------------------------------------------
// Fused QKV MFMA GEMM (unchanged).
// ---------------------------------------------------------------------------
__global__ __launch_bounds__(256) void qkv_mfma_kernel(
    const u16* __restrict__ Xb, const u16* __restrict__ Wt,
    const float* __restrict__ bq, const float* __restrict__ bk,
    const float* __restrict__ bv,
    u16* __restrict__ qb, u16* __restrict__ kb, u16* __restrict__ vt) {
  const int bn = blockIdx.x;
  const int bm = blockIdx.y;
  const int zi = bn / 6;

  __shared__ u16 As[64 * 64];
  __shared__ u16 Bs[128 * 64];

  const int tid  = threadIdx.x;
  const int lane = tid & 63;
  const int w    = tid >> 6;
  const int g    = lane >> 4;
  const int ln   = lane & 15;
  const int wm   = (w >> 1) * 32;
  const int wn   = (w & 1) * 64;

  f32x4 acc[2][4] = {};

  const int srow = tid >> 3;
  const int scol = (tid & 7) * 8;
  const u16* Ag = Xb + (size_t)(bm * 64 + srow) * HIDD + scol;
  const u16* Bg = Wt + (size_t)(bn * 128 + srow) * HIDD + scol;

  for (int k0 = 0; k0 < HIDD; k0 += 64) {
    if (k0) __syncthreads();
#pragma unroll
    for (int p = 0; p < 2; ++p) {
      const int r = srow + 32 * p;
      const int sw = (r & 7) << 3;
      *(u16x8*)&As[r * 64 + (scol ^ sw)] =
          *(const u16x8*)&Ag[(size_t)(32 * p) * HIDD + k0];
    }
#pragma unroll
    for (int p = 0; p < 4; ++p) {
      const int r = srow + 32 * p;
      const int sw = (r & 7) << 3;
      *(u16x8*)&Bs[r * 64 + (scol ^ sw)] =
          *(const u16x8*)&Bg[(size_t)(32 * p) * HIDD + k0];
    }
    __syncthreads();

    bf8 af[2][2], bfr[4][2];
#pragma unroll
    for (int f = 0; f < 2; ++f)
#pragma unroll
      for (int kk = 0; kk < 2; ++kk)
        af[f][kk] = ldfrag(As, wm + 16 * f + ln, kk * 32 + g * 8);
#pragma unroll
    for (int f = 0; f < 4; ++f)
#pragma unroll
      for (int kk = 0; kk < 2; ++kk)
        bfr[f][kk] = ldfrag(Bs, wn + 16 * f + ln, kk * 32 + g * 8);
    if (zi < 2) {
#pragma unroll
      for (int mf = 0; mf < 2; ++mf)
#pragma unroll
        for (int nf = 0; nf < 4; ++nf)
#pragma unroll
          for (int kk = 0; kk < 2; ++kk)
            acc[mf][nf] = __builtin_amdgcn_mfma_f32_16x16x32_bf16(
                bfr[nf][kk], af[mf][kk], acc[mf][nf], 0, 0, 0);
    } else {
#pragma unroll
      for (int mf = 0; mf < 2; ++mf)
#pragma unroll
        for (int nf = 0; nf < 4; ++nf)
#pragma unroll
          for (int kk = 0; kk < 2; ++kk)
            acc[mf][nf] = __builtin_amdgcn_mfma_f32_16x16x32_bf16(
                af[mf][kk], bfr[nf][kk], acc[mf][nf], 0, 0, 0);
    }
  }

  const int mrow  = bm * 64 + wm;
  const int nbase = (bn % 6) * 128 + wn;
  const int h     = nbase >> 6;

  if (zi < 2) {
    const float* __restrict__ bias = zi ? bk : bq;
    u16* __restrict__ outp = zi ? kb : qb;
#pragma unroll
    for (int nf = 0; nf < 4; ++nf) {
      const int d0 = 16 * nf + 4 * g;
      float4 bi = *(const float4*)&bias[nbase + d0];
#pragma unroll
      for (int mf = 0; mf < 2; ++mf) {
        const int m = mrow + 16 * mf + ln;
        const int b = m >> 10, s = m & 1023;
        u16x4 o;
        o[0] = f2bf(acc[mf][nf][0] + bi.x);
        o[1] = f2bf(acc[mf][nf][1] + bi.y);
        o[2] = f2bf(acc[mf][nf][2] + bi.z);
        o[3] = f2bf(acc[mf][nf][3] + bi.w);
        *(u16x4*)&outp[(((size_t)(b * NHH + h)) * SS + s) * HDD + d0] = o;
      }
    }
  } else {
#pragma unroll
    for (int nf = 0; nf < 4; ++nf) {
      const int d = 16 * nf + ln;
      const float bi = bv[nbase + d];
#pragma unroll
      for (int mf = 0; mf < 2; ++mf) {
        const int m = mrow + 16 * mf + 4 * g;
        const int b = m >> 10, s = m & 1023;
        u16x4 o;
        o[0] = f2bf(acc[mf][nf][0] + bi);
        o[1] = f2bf(acc[mf][nf][1] + bi);
        o[2] = f2bf(acc[mf][nf][2] + bi);
        o[3] = f2bf(acc[mf][nf][3] + bi);
        *(u16x4*)&vt[(((size_t)(b * NHH + h)) * HDD + d) * SS + s] = o;
      }
    }
  }
}

// ---------------------------------------------------------------------------
// ABLATION attn kernel (R7 structure). ABL bits disable phases:
//  1=Toeplitz-bias  2=mask-loads  4=softmax+exchange  8=QK-MFMA
//  16=PV-MFMA  32=K/V-staging. ABL=0 is the full (correct) kernel.
// DCE guards: pa depends on sc in all variants; acc stored via merge path.
// ---------------------------------------------------------------------------
template <int ABL>
__global__ __launch_bounds__(256, 3) void attn_kernel(
    const u16* __restrict__ qbg, const u16* __restrict__ kbg,
    const u16* __restrict__ vtg, const u16* __restrict__ eb,
    const float* __restrict__ am, const u16* __restrict__ smb,
    const float* __restrict__ selp, float* __restrict__ outp) {
  constexpr bool NOBIAS = (ABL & 1) != 0;
  constexpr bool NOMASK = (ABL & 2) != 0;
  constexpr bool NOSM   = (ABL & 4) != 0;
  constexpr bool NOQK   = (ABL & 8) != 0;
  constexpr bool NOPV   = (ABL & 16) != 0;
  constexpr bool NOSTG  = (ABL & 32) != 0;

  const int bid  = blockIdx.x;
  const int xcd  = bid & 7;
  const int idx  = bid >> 3;
  const int inner = idx & 31;
  const int grp  = idx >> 5;
  const int hg   = grp * 8 + xcd;
  const int h    = hg % NHH;
  const int b    = hg / NHH;
  const int l0   = inner * 32;

  const int bh = b * NHH + h;
  const size_t hoff = (size_t)bh * SS * HDD;

  __shared__ __align__(16) u16 smbuf[16384];
  __shared__ __align__(4)  u16 tbuf[4 * 80 * 20];

  const int tid  = threadIdx.x;
  const int lane = tid & 63;
  const int w    = tid >> 6;
  const int p    = w >> 1;
  const int wp   = w & 1;
  const int g    = lane >> 4;
  const int ln   = lane & 15;

  if (tid == 0) tbuf[0] = 0;  // keep LDS footprint constant across variants

  u16* ksw = smbuf + p * 4096;
  u16* vsw = smbuf + 8192 + p * 4096;
  u16* Tw  = tbuf + w * (80 * 20);

  bf8 qf[2];
  {
    const u16* qp = qbg + hoff + (size_t)(l0 + 16 * wp + ln) * HDD + g * 8;
    qf[0] = *(const bf8*)(qp);
    qf[1] = *(const bf8*)(qp + 32);
  }

  f32x4 acc1[4] = {}, acc2[4] = {};
  float m1 = -INFINITY, m2 = -INFINITY, sum1 = 0.f, sum2 = 0.f;

  const int tid128 = tid & 127;
  const int rr = tid128 >> 2;
  const int cc = (tid128 & 3) << 4;
  const int S0i = ((lane & 16) << 1) | ln;
  const int S1i = S0i + 16;
  const bool ghi = (lane & 32) != 0;

  const u16* kgp0 = kbg + hoff;
  const u16* vgp0 = vtg + hoff;

  u16x8 kr[2][2], vr[2][2];
  if constexpr (!NOSTG) {
    const int r0 = 512 * p;
#pragma unroll
    for (int pp = 0; pp < 2; ++pp) {
      const int r = rr + 32 * pp;
      kr[pp][0] = *(const u16x8*)&kgp0[(size_t)(r0 + r) * HDD + cc];
      kr[pp][1] = *(const u16x8*)&kgp0[(size_t)(r0 + r) * HDD + cc + 8];
      vr[pp][0] = *(const u16x8*)&vgp0[(size_t)r * SS + r0 + cc];
      vr[pp][1] = *(const u16x8*)&vgp0[(size_t)r * SS + r0 + cc + 8];
    }
  }

  for (int t = 0; t < 8; ++t) {
    const int r0 = 512 * p + 64 * t;

    bf8 ef[5][2];
    if constexpr (!NOBIAS) {
      const int W0 = l0 + 16 * wp - r0 + 960;
#pragma unroll
      for (int c5 = 0; c5 < 5; ++c5) {
        const int gr = min(W0 + 16 * c5 + ln, 2046);
        const u16* ep = eb + (size_t)gr * HDD + g * 8;
        ef[c5][0] = *(const bf8*)(ep);
        ef[c5][1] = *(const bf8*)(ep + 32);
      }
    }
    f32x4 amv[4];
    u16x4 smv[4];
    if constexpr (!NOMASK) {
#pragma unroll
      for (int ct = 0; ct < 4; ++ct) {
        amv[ct] = *(const f32x4*)&am[(b << 10) + r0 + 16 * ct + 4 * g];
        smv[ct] = *(const u16x4*)&smb[(size_t)(l0 + 16 * wp + ln) * SS +
                                      r0 + 16 * ct + 4 * g];
      }
    } else {
#pragma unroll
      for (int ct = 0; ct < 4; ++ct) {
        amv[ct] = f32x4{0.f, 0.f, 0.f, 0.f};
        smv[ct] = u16x4{0x3f80, 0x3f80, 0x3f80, 0x3f80};
      }
    }

    __syncthreads();
    if constexpr (!NOSTG) {
#pragma unroll
      for (int pp = 0; pp < 2; ++pp) {
        const int r = rr + 32 * pp;
        const int sw = (r & 7) << 3;
        *(u16x8*)&ksw[r * 64 + (cc ^ sw)] = kr[pp][0];
        *(u16x8*)&ksw[r * 64 + ((cc + 8) ^ sw)] = kr[pp][1];
        *(u16x8*)&vsw[r * 64 + (cc ^ sw)] = vr[pp][0];
        *(u16x8*)&vsw[r * 64 + ((cc + 8) ^ sw)] = vr[pp][1];
      }
    }
    __syncthreads();

    if constexpr (!NOSTG) {
      if (t < 7) {
        const int rn = r0 + 64;
#pragma unroll
        for (int pp = 0; pp < 2; ++pp) {
          const int r = rr + 32 * pp;
          kr[pp][0] = *(const u16x8*)&kgp0[(size_t)(rn + r) * HDD + cc];
          kr[pp][1] = *(const u16x8*)&kgp0[(size_t)(rn + r) * HDD + cc + 8];
          vr[pp][0] = *(const u16x8*)&vgp0[(size_t)r * SS + rn + cc];
          vr[pp][1] = *(const u16x8*)&vgp0[(size_t)r * SS + rn + cc + 8];
        }
      }
    }

    __builtin_amdgcn_s_setprio(1);
    if constexpr (!NOBIAS) {
#pragma unroll
      for (int c5 = 0; c5 < 5; ++c5) {
        f32x4 x = {0.f, 0.f, 0.f, 0.f};
        x = __builtin_amdgcn_mfma_f32_16x16x32_bf16(ef[c5][0], qf[0], x, 0, 0, 0);
        x = __builtin_amdgcn_mfma_f32_16x16x32_bf16(ef[c5][1], qf[1], x, 0, 0, 0);
#pragma unroll
        for (int i = 0; i < 4; ++i)
          Tw[(16 * c5 + 4 * g + i) * 20 + ln] = f2bf(x[i]);
      }
    }
    f32x4 sc[4];
    if constexpr (!NOQK) {
#pragma unroll
      for (int ct = 0; ct < 4; ++ct) {
        f32x4 x = {0.f, 0.f, 0.f, 0.f};
#pragma unroll
        for (int kk = 0; kk < 2; ++kk)
          x = __builtin_amdgcn_mfma_f32_16x16x32_bf16(
              ldfrag(ksw, ct * 16 + ln, kk * 32 + g * 8), qf[kk], x, 0, 0, 0);
        sc[ct] = x;
      }
    } else {
#pragma unroll
      for (int ct = 0; ct < 4; ++ct) sc[ct] = f32x4{0.f, 0.f, 0.f, 0.f};
      // keep qf alive
      asm volatile("" ::"v"((int)qf[0][0]), "v"((int)qf[1][0]));
    }
    __builtin_amdgcn_s_setprio(0);

    float s1r[4][4], s2r[4][4];
#pragma unroll
    for (int ct = 0; ct < 4; ++ct)
#pragma unroll
      for (int i = 0; i < 4; ++i) {
        float tb;
        if constexpr (!NOBIAS) {
          const int e = ln + 63 - 16 * ct - 4 * g - i;
          tb = bf2f(Tw[e * 20 + ln]);
        } else {
          tb = 0.f;
        }
        const float s1 = (sc[ct][i] + tb) * 0.125f + amv[ct][i];
        s1r[ct][i] = s1;
        s2r[ct][i] = s1 * bf2f(smv[ct][i]) + amv[ct][i];
      }

    bf8 pa1[2], pa2[2];
    if constexpr (NOSM) {
      // pack scores directly (keeps QK->pa dependency, skips softmax cost)
      u32 pk1[4][2], pk2[4][2];
#pragma unroll
      for (int ct = 0; ct < 4; ++ct) {
        pk1[ct][0] = (u32)f2bf(s1r[ct][0]) | ((u32)f2bf(s1r[ct][1]) << 16);
        pk1[ct][1] = (u32)f2bf(s1r[ct][2]) | ((u32)f2bf(s1r[ct][3]) << 16);
        pk2[ct][0] = (u32)f2bf(s2r[ct][0]) | ((u32)f2bf(s2r[ct][1]) << 16);
        pk2[ct][1] = (u32)f2bf(s2r[ct][2]) | ((u32)f2bf(s2r[ct][3]) << 16);
      }
      sum1 += s1r[0][0];
      sum2 += s2r[0][0];
      m1 = fmaxf(m1, s1r[0][0]);
      m2 = fmaxf(m2, s2r[0][0]);
#pragma unroll
      for (int kk = 0; kk < 2; ++kk) {
        union { u32 u[4]; bf8 v; } f1, f2c;
        f1.u[0] = pk1[2 * kk][0];  f1.u[1] = pk1[2 * kk][1];
        f1.u[2] = pk1[2 * kk + 1][0]; f1.u[3] = pk1[2 * kk + 1][1];
        f2c.u[0] = pk2[2 * kk][0]; f2c.u[1] = pk2[2 * kk][1];
        f2c.u[2] = pk2[2 * kk + 1][0]; f2c.u[3] = pk2[2 * kk + 1][1];
        pa1[kk] = f1.v;
        pa2[kk] = f2c.v;
      }
    } else {
      // ---- branch 1 softmax ----
      {
        float mx = s1r[0][0];
#pragma unroll
        for (int ct = 0; ct < 4; ++ct)
#pragma unroll
          for (int i = 0; i < 4; ++i) mx = fmaxf(mx, s1r[ct][i]);
        mx = fmaxf(mx, __shfl_xor(mx, 16, 64));
        mx = fmaxf(mx, __shfl_xor(mx, 32, 64));
        const float mn = fmaxf(m1, mx);
        const float scl = __expf(m1 - mn);
        m1 = mn;
        float rs = 0.f;
        u32 pk[4][2];
#pragma unroll
        for (int ct = 0; ct < 4; ++ct) {
          const float p0 = __expf(s1r[ct][0] - mn);
          const float p1 = __expf(s1r[ct][1] - mn);
          const float p2 = __expf(s1r[ct][2] - mn);
          const float p3 = __expf(s1r[ct][3] - mn);
          rs += (p0 + p1) + (p2 + p3);
          pk[ct][0] = (u32)f2bf(p0) | ((u32)f2bf(p1) << 16);
          pk[ct][1] = (u32)f2bf(p2) | ((u32)f2bf(p3) << 16);
        }
        rs += __shfl_xor(rs, 16, 64);
        rs += __shfl_xor(rs, 32, 64);
        sum1 = sum1 * scl + rs;
#pragma unroll
        for (int i = 0; i < 4; ++i) {
          const float s = __shfl(scl, (lane & 48) + 4 * g + i, 64);
#pragma unroll
          for (int dt = 0; dt < 4; ++dt) acc1[dt][i] *= s;
        }
#pragma unroll
        for (int kk = 0; kk < 2; ++kk) {
          union { u32 u[4]; bf8 v; } f;
          const int cA = 2 * kk, cB = 2 * kk + 1;
          u32 a, bb;
          a = (u32)__shfl((int)pk[cA][0], S0i, 64);
          bb = (u32)__shfl((int)pk[cB][0], S0i, 64);
          f.u[0] = ghi ? bb : a;
          a = (u32)__shfl((int)pk[cA][1], S0i, 64);
          bb = (u32)__shfl((int)pk[cB][1], S0i, 64);
          f.u[1] = ghi ? bb : a;
          a = (u32)__shfl((int)pk[cA][0], S1i, 64);
          bb = (u32)__shfl((int)pk[cB][0], S1i, 64);
          f.u[2] = ghi ? bb : a;
          a = (u32)__shfl((int)pk[cA][1], S1i, 64);
          bb = (u32)__shfl((int)pk[cB][1], S1i, 64);
          f.u[3] = ghi ? bb : a;
          pa1[kk] = f.v;
        }
      }
      // ---- branch 2 softmax ----
      {
        float mx = s2r[0][0];
#pragma unroll
        for (int ct = 0; ct < 4; ++ct)
#pragma unroll
          for (int i = 0; i < 4; ++i) mx = fmaxf(mx, s2r[ct][i]);
        mx = fmaxf(mx, __shfl_xor(mx, 16, 64));
        mx = fmaxf(mx, __shfl_xor(mx, 32, 64));
        const float mn = fmaxf(m2, mx);
        const float scl = __expf(m2 - mn);
        m2 = mn;
        float rs = 0.f;
        u32 pk[4][2];
#pragma unroll
        for (int ct = 0; ct < 4; ++ct) {
          const float p0 = __expf(s2r[ct][0] - mn);
          const float p1 = __expf(s2r[ct][1] - mn);
          const float p2 = __expf(s2r[ct][2] - mn);
          const float p3 = __expf(s2r[ct][3] - mn);
          rs += (p0 + p1) + (p2 + p3);
          pk[ct][0] = (u32)f2bf(p0) | ((u32)f2bf(p1) << 16);
          pk[ct][1] = (u32)f2bf(p2) | ((u32)f2bf(p3) << 16);
        }
        rs += __shfl_xor(rs, 16, 64);
        rs += __shfl_xor(rs, 32, 64);
        sum2 = sum2 * scl + rs;
#pragma unroll
        for (int i = 0; i < 4; ++i) {
          const float s = __shfl(scl, (lane & 48) + 4 * g + i, 64);
#pragma unroll
          for (int dt = 0; dt < 4; ++dt) acc2[dt][i] *= s;
        }
#pragma unroll
        for (int kk = 0; kk < 2; ++kk) {
          union { u32 u[4]; bf8 v; } f;
          const int cA = 2 * kk, cB = 2 * kk + 1;
          u32 a, bb;
          a = (u32)__shfl((int)pk[cA][0], S0i, 64);
          bb = (u32)__shfl((int)pk[cB][0], S0i, 64);
          f.u[0] = ghi ? bb : a;
          a = (u32)__shfl((int)pk[cA][1], S0i, 64);
          bb = (u32)__shfl((int)pk[cB][1], S0i, 64);
          f.u[1] = ghi ? bb : a;
          a = (u32)__shfl((int)pk[cA][0], S1i, 64);
          bb = (u32)__shfl((int)pk[cB][0], S1i, 64);
          f.u[2] = ghi ? bb : a;
          a = (u32)__shfl((int)pk[cA][1], S1i, 64);
          bb = (u32)__shfl((int)pk[cB][1], S1i, 64);
          f.u[3] = ghi ? bb : a;
          pa2[kk] = f.v;
        }
      }
    }

    if constexpr (!NOPV) {
      __builtin_amdgcn_s_setprio(1);
#pragma unroll
      for (int kk = 0; kk < 2; ++kk) {
#pragma unroll
        for (int dt = 0; dt < 4; ++dt) {
          bf8 vb = ldfrag(vsw, dt * 16 + ln, kk * 32 + g * 8);
          acc1[dt] = __builtin_amdgcn_mfma_f32_16x16x32_bf16(pa1[kk], vb, acc1[dt], 0, 0, 0);
          acc2[dt] = __builtin_amdgcn_mfma_f32_16x16x32_bf16(pa2[kk], vb, acc2[dt], 0, 0, 0);
        }
      }
      __builtin_amdgcn_s_setprio(0);
    } else {
      // keep pa alive without MFMA cost
      acc1[0][0] += (float)pa1[0][0] * 1e-30f;
      acc2[0][0] += (float)pa2[0][0] * 1e-30f;
    }
  }

  __syncthreads();
  float* scr = (float*)smbuf;
  if (p == 1) {
#pragma unroll
    for (int i = 0; i < 4; ++i) {
      const int row = 4 * g + i;
#pragma unroll
      for (int dt = 0; dt < 4; ++dt) {
        scr[wp * 1024 + row * 64 + dt * 16 + ln] = acc1[dt][i];
        scr[2048 + wp * 1024 + row * 64 + dt * 16 + ln] = acc2[dt][i];
      }
    }
    if (g == 0) {
      const int sb = 4096 + (wp * 16 + ln) * 4;
      scr[sb + 0] = m1;
      scr[sb + 1] = sum1;
      scr[sb + 2] = m2;
      scr[sb + 3] = sum2;
    }
  }
  __syncthreads();
  if (p == 0) {
    const int sb = 4096 + (wp * 16 + ln) * 4;
    const float mB1 = scr[sb + 0], sB1 = scr[sb + 1];
    const float mB2 = scr[sb + 2], sB2 = scr[sb + 3];
    const float M1 = fmaxf(m1, mB1);
    const float e1A = __expf(m1 - M1), e1B = __expf(mB1 - M1);
    const float inv1 = 1.f / (sum1 * e1A + sB1 * e1B);
    const float a1 = e1A * inv1, c1 = e1B * inv1;
    const float M2 = fmaxf(m2, mB2);
    const float e2A = __expf(m2 - M2), e2B = __expf(mB2 - M2);
    const float inv2 = 1.f / (sum2 * e2A + sB2 * e2B);
    const float a2 = e2A * inv2, c2 = e2B * inv2;
#pragma unroll
    for (int i = 0; i < 4; ++i) {
      const int src = (lane & 48) + 4 * g + i;
      const float a1s = __shfl(a1, src, 64), c1s = __shfl(c1, src, 64);
      const float a2s = __shfl(a2, src, 64), c2s = __shfl(c2, src, 64);
      const int row = 4 * g + i;
      const int lg = l0 + 16 * wp + row;
      const float se = selp[(b << 10) + lg];
#pragma unroll
      for (int dt = 0; dt < 4; ++dt) {
        const float aB1 = scr[wp * 1024 + row * 64 + dt * 16 + ln];
        const float aB2 = scr[2048 + wp * 1024 + row * 64 + dt * 16 + ln];
        const float o1 = acc1[dt][i] * a1s + aB1 * c1s;
        const float o2 = acc2[dt][i] * a2s + aB2 * c2s;
        outp[((size_t)((b << 10) + lg)) * HIDD + h * HDD + dt * 16 + ln] =
            se * o2 + (1.f - se) * o1;
      }
    }
  }
}

extern "C" void kernel_launch(void* const* d_in, const int* in_sizes, int n_in,
                              void* d_out, int out_size, void* d_ws, size_t ws_size,
                              hipStream_t stream) {
  const float* hidden = (const float*)d_in[0];
  const float* am     = (const float*)d_in[1];
  const float* smask  = (const float*)d_in[2];
  const float* selp   = (const float*)d_in[3];
  const float* Wq     = (const float*)d_in[4];
  const float* bq     = (const float*)d_in[5];
  const float* Wk     = (const float*)d_in[6];
  const float* bk     = (const float*)d_in[7];
  const float* Wv     = (const float*)d_in[8];
  const float* bv     = (const float*)d_in[9];
  const float* demb   = (const float*)d_in[10];
  float* out = (float*)d_out;

  u16* wsp = (u16*)d_ws;
  const size_t NEL = (size_t)BB * NHH * SS * HDD;  // 1572864
  u16* Xb  = wsp;
  u16* Wt  = Xb + (size_t)2048 * HIDD;
  u16* qbw = Wt + (size_t)3 * HIDD * HIDD;
  u16* kbw = qbw + NEL;
  u16* vtw = kbw + NEL;
  u16* ebw = vtw + NEL;
  u16* smb = ebw + (size_t)2047 * HDD;
  float* dummy = (float*)(smb + (size_t)SS * SS);  // 6.3MB scratch output

  xconv_kernel<<<768, 256, 0, stream>>>(hidden, Xb);
  dim3 gw(HIDD / 64, HIDD / 64, 3);
  wtconv_kernel<<<gw, 256, 0, stream>>>(Wq, Wk, Wv, Wt);
  econv_kernel<<<64, 256, 0, stream>>>(demb, ebw);
  sconv_kernel<<<512, 256, 0, stream>>>(smask, smb);

  dim3 g1(18, 32);
  qkv_mfma_kernel<<<g1, 256, 0, stream>>>(Xb, Wt, bq, bk, bv, qbw, kbw, vtw);

  // --- ablation sweep (writes to dummy; per-dispatch dur via rocprof) ---
  attn_kernel<1><<<768, 256, 0, stream>>>(qbw, kbw, vtw, ebw, am, smb, selp, dummy);   // no bias
  attn_kernel<2><<<768, 256, 0, stream>>>(qbw, kbw, vtw, ebw, am, smb, selp, dummy);   // no masks
  attn_kernel<4><<<768, 256, 0, stream>>>(qbw, kbw, vtw, ebw, am, smb, selp, dummy);   // no softmax
  attn_kernel<8><<<768, 256, 0, stream>>>(qbw, kbw, vtw, ebw, am, smb, selp, dummy);   // no QK
  attn_kernel<16><<<768, 256, 0, stream>>>(qbw, kbw, vtw, ebw, am, smb, selp, dummy);  // no PV
  attn_kernel<32><<<768, 256, 0, stream>>>(qbw, kbw, vtw, ebw, am, smb, selp, dummy);  // no stage

  // --- full kernel produces the real output ---
  attn_kernel<0><<<768, 256, 0, stream>>>(qbw, kbw, vtw, ebw, am, smb, selp, out);
}

// Round 10
// 300.640 us; speedup vs baseline: 1.5472x; 1.5472x over previous
//
#include <hip/hip_runtime.h>
#include <hip/hip_bf16.h>
#include <math.h>

#define BB   2
#define SS   1024
#define HIDD 768
#define NHH  12
#define HDD  64

typedef float f32x4 __attribute__((ext_vector_type(4)));
typedef short bf8   __attribute__((ext_vector_type(8)));   // 8 bf16 (bit pattern)
typedef unsigned short u16;
typedef unsigned int u32;
typedef u16 u16x8 __attribute__((ext_vector_type(8)));
typedef u16 u16x4 __attribute__((ext_vector_type(4)));

__device__ __forceinline__ u16 f2bf(float x) {  // RNE f32->bf16
  unsigned int u = __float_as_uint(x);
  u += 0x7fffu + ((u >> 16) & 1u);
  return (u16)(u >> 16);
}
__device__ __forceinline__ float bf2f(u16 x) {
  return __uint_as_float(((u32)x) << 16);
}

__device__ __forceinline__ bf8 ldfrag(const u16* t, int row, int kc) {
  return *(const bf8*)&t[row * 64 + (kc ^ ((row & 7) << 3))];
}

// ---------------------------------------------------------------------------
// Prep kernels (unchanged).
// ---------------------------------------------------------------------------
__global__ __launch_bounds__(256) void xconv_kernel(const float* __restrict__ X,
                                                    u16* __restrict__ Xb) {
  int i = (blockIdx.x * 256 + threadIdx.x) * 8;
  float4 a = *(const float4*)&X[i];
  float4 b = *(const float4*)&X[i + 4];
  u16x8 o;
  o[0] = f2bf(a.x); o[1] = f2bf(a.y); o[2] = f2bf(a.z); o[3] = f2bf(a.w);
  o[4] = f2bf(b.x); o[5] = f2bf(b.y); o[6] = f2bf(b.z); o[7] = f2bf(b.w);
  *(u16x8*)&Xb[i] = o;
}

__global__ __launch_bounds__(256) void wtconv_kernel(
    const float* __restrict__ Wq, const float* __restrict__ Wk,
    const float* __restrict__ Wv, u16* __restrict__ Wt) {
  const int zi = blockIdx.z;
  const float* __restrict__ W = (zi == 0) ? Wq : (zi == 1 ? Wk : Wv);
  const int n0 = blockIdx.x * 64;
  const int k0 = blockIdx.y * 64;
  __shared__ float t[64][65];
  const int tid = threadIdx.x;
  {
    const int kl = tid >> 4;
    const int nl = (tid & 15) * 4;
#pragma unroll
    for (int p = 0; p < 4; ++p) {
      float4 v = *(const float4*)&W[(size_t)(k0 + kl + 16 * p) * HIDD + n0 + nl];
      t[kl + 16 * p][nl + 0] = v.x;
      t[kl + 16 * p][nl + 1] = v.y;
      t[kl + 16 * p][nl + 2] = v.z;
      t[kl + 16 * p][nl + 3] = v.w;
    }
  }
  __syncthreads();
  {
    const int nl = tid >> 4;
    const int cl = (tid & 15) * 4;
#pragma unroll
    for (int p = 0; p < 4; ++p) {
      const int n = nl + 16 * p;
      u16x4 o;
      o[0] = f2bf(t[cl + 0][n]);
      o[1] = f2bf(t[cl + 1][n]);
      o[2] = f2bf(t[cl + 2][n]);
      o[3] = f2bf(t[cl + 3][n]);
      *(u16x4*)&Wt[(size_t)(zi * HIDD + n0 + n) * HIDD + k0 + cl] = o;
    }
  }
}

__global__ __launch_bounds__(256) void econv_kernel(const float* __restrict__ demb,
                                                    u16* __restrict__ eb) {
  int i = (blockIdx.x * 256 + threadIdx.x) * 8;
  if (i < 2047 * HDD) {
    float4 a = *(const float4*)&demb[i];
    float4 b = *(const float4*)&demb[i + 4];
    u16x8 o;
    o[0] = f2bf(a.x); o[1] = f2bf(a.y); o[2] = f2bf(a.z); o[3] = f2bf(a.w);
    o[4] = f2bf(b.x); o[5] = f2bf(b.y); o[6] = f2bf(b.z); o[7] = f2bf(b.w);
    *(u16x8*)&eb[i] = o;
  }
}

__global__ __launch_bounds__(256) void sconv_kernel(const float* __restrict__ sm,
                                                    u16* __restrict__ smb) {
  int i = (blockIdx.x * 256 + threadIdx.x) * 8;
  float4 a = *(const float4*)&sm[i];
  float4 b = *(const float4*)&sm[i + 4];
  u16x8 o;
  o[0] = f2bf(a.x); o[1] = f2bf(a.y); o[2] = f2bf(a.z); o[3] = f2bf(a.w);
  o[4] = f2bf(b.x); o[5] = f2bf(b.y); o[6] = f2bf(b.z); o[7] = f2bf(b.w);
  *(u16x8*)&smb[i] = o;
}

// ---------------------------------------------------------------------------
// Fused QKV MFMA GEMM (unchanged).
// ---------------------------------------------------------------------------
__global__ __launch_bounds__(256) void qkv_mfma_kernel(
    const u16* __restrict__ Xb, const u16* __restrict__ Wt,
    const float* __restrict__ bq, const float* __restrict__ bk,
    const float* __restrict__ bv,
    u16* __restrict__ qb, u16* __restrict__ kb, u16* __restrict__ vt) {
  const int bn = blockIdx.x;
  const int bm = blockIdx.y;
  const int zi = bn / 6;

  __shared__ u16 As[64 * 64];
  __shared__ u16 Bs[128 * 64];

  const int tid  = threadIdx.x;
  const int lane = tid & 63;
  const int w    = tid >> 6;
  const int g    = lane >> 4;
  const int ln   = lane & 15;
  const int wm   = (w >> 1) * 32;
  const int wn   = (w & 1) * 64;

  f32x4 acc[2][4] = {};

  const int srow = tid >> 3;
  const int scol = (tid & 7) * 8;
  const u16* Ag = Xb + (size_t)(bm * 64 + srow) * HIDD + scol;
  const u16* Bg = Wt + (size_t)(bn * 128 + srow) * HIDD + scol;

  for (int k0 = 0; k0 < HIDD; k0 += 64) {
    if (k0) __syncthreads();
#pragma unroll
    for (int p = 0; p < 2; ++p) {
      const int r = srow + 32 * p;
      const int sw = (r & 7) << 3;
      *(u16x8*)&As[r * 64 + (scol ^ sw)] =
          *(const u16x8*)&Ag[(size_t)(32 * p) * HIDD + k0];
    }
#pragma unroll
    for (int p = 0; p < 4; ++p) {
      const int r = srow + 32 * p;
      const int sw = (r & 7) << 3;
      *(u16x8*)&Bs[r * 64 + (scol ^ sw)] =
          *(const u16x8*)&Bg[(size_t)(32 * p) * HIDD + k0];
    }
    __syncthreads();

    bf8 af[2][2], bfr[4][2];
#pragma unroll
    for (int f = 0; f < 2; ++f)
#pragma unroll
      for (int kk = 0; kk < 2; ++kk)
        af[f][kk] = ldfrag(As, wm + 16 * f + ln, kk * 32 + g * 8);
#pragma unroll
    for (int f = 0; f < 4; ++f)
#pragma unroll
      for (int kk = 0; kk < 2; ++kk)
        bfr[f][kk] = ldfrag(Bs, wn + 16 * f + ln, kk * 32 + g * 8);
    if (zi < 2) {
#pragma unroll
      for (int mf = 0; mf < 2; ++mf)
#pragma unroll
        for (int nf = 0; nf < 4; ++nf)
#pragma unroll
          for (int kk = 0; kk < 2; ++kk)
            acc[mf][nf] = __builtin_amdgcn_mfma_f32_16x16x32_bf16(
                bfr[nf][kk], af[mf][kk], acc[mf][nf], 0, 0, 0);
    } else {
#pragma unroll
      for (int mf = 0; mf < 2; ++mf)
#pragma unroll
        for (int nf = 0; nf < 4; ++nf)
#pragma unroll
          for (int kk = 0; kk < 2; ++kk)
            acc[mf][nf] = __builtin_amdgcn_mfma_f32_16x16x32_bf16(
                af[mf][kk], bfr[nf][kk], acc[mf][nf], 0, 0, 0);
    }
  }

  const int mrow  = bm * 64 + wm;
  const int nbase = (bn % 6) * 128 + wn;
  const int h     = nbase >> 6;

  if (zi < 2) {
    const float* __restrict__ bias = zi ? bk : bq;
    u16* __restrict__ outp = zi ? kb : qb;
#pragma unroll
    for (int nf = 0; nf < 4; ++nf) {
      const int d0 = 16 * nf + 4 * g;
      float4 bi = *(const float4*)&bias[nbase + d0];
#pragma unroll
      for (int mf = 0; mf < 2; ++mf) {
        const int m = mrow + 16 * mf + ln;
        const int b = m >> 10, s = m & 1023;
        u16x4 o;
        o[0] = f2bf(acc[mf][nf][0] + bi.x);
        o[1] = f2bf(acc[mf][nf][1] + bi.y);
        o[2] = f2bf(acc[mf][nf][2] + bi.z);
        o[3] = f2bf(acc[mf][nf][3] + bi.w);
        *(u16x4*)&outp[(((size_t)(b * NHH + h)) * SS + s) * HDD + d0] = o;
      }
    }
  } else {
#pragma unroll
    for (int nf = 0; nf < 4; ++nf) {
      const int d = 16 * nf + ln;
      const float bi = bv[nbase + d];
#pragma unroll
      for (int mf = 0; mf < 2; ++mf) {
        const int m = mrow + 16 * mf + 4 * g;
        const int b = m >> 10, s = m & 1023;
        u16x4 o;
        o[0] = f2bf(acc[mf][nf][0] + bi);
        o[1] = f2bf(acc[mf][nf][1] + bi);
        o[2] = f2bf(acc[mf][nf][2] + bi);
        o[3] = f2bf(acc[mf][nf][3] + bi);
        *(u16x4*)&vt[(((size_t)(b * NHH + h)) * HDD + d) * SS + s] = o;
      }
    }
  }
}

// ---------------------------------------------------------------------------
// attn v10: occupancy-first. QBLK=16 (grid 1536 = 6 blocks/CU), 4 waves
// split-K x4 (wave w: r in [256w, 256w+256), 8 tiles of KVBLK=32).
// K/E frags direct from global (L2, XCD-local); V wave-private LDS (R8
// scheme); T-bias swapped MFMA + per-wave LDS (48x20). R8-validated
// defer-max softmax + P exchange. Barrier-free main loop; 4-way merge.
// LDS 25.6KB -> 6 blocks/CU = 24 waves/CU.
// ---------------------------------------------------------------------------
__global__ __launch_bounds__(256, 6) void attn_kernel(
    const u16* __restrict__ qbg,     // [B*NH][S][64] bf16
    const u16* __restrict__ kbg,     // [B*NH][S][64] bf16
    const u16* __restrict__ vtg,     // [B*NH][64][S] bf16
    const u16* __restrict__ eb,      // [2047][64] bf16
    const float* __restrict__ am,    // [B][S]
    const u16* __restrict__ smb,     // [S][S] bf16
    const float* __restrict__ selp,  // [B][S]
    float* __restrict__ out) {       // [B][S][768]
  // XCD-bijective swizzle: all 64 q-tiles of one (b,h) share bid&7.
  const int bid  = blockIdx.x;          // 0..1535
  const int xcd  = bid & 7;
  const int idx  = bid >> 3;            // 0..191
  const int inner = idx & 63;           // q-tile
  const int grp  = idx >> 6;            // 0..2
  const int hg   = grp * 8 + xcd;       // 0..23
  const int h    = hg % NHH;
  const int b    = hg / NHH;
  const int l0   = inner * 16;

  const int bh = b * NHH + h;
  const size_t hoff = (size_t)bh * SS * HDD;

  // 25.6KB: V 4x[64][32] (8192 u16) | T 4x[48][20] (3840 u16) | merge overlay
  __shared__ __align__(16) u16 smbuf[12800];

  const int tid  = threadIdx.x;
  const int lane = tid & 63;
  const int w    = tid >> 6;   // 0..3 = r-quarter
  const int g    = lane >> 4;
  const int ln   = lane & 15;

  u16* vsw = smbuf + w * 2048;          // [64 d][32 r] swizzled
  u16* Tw  = smbuf + 8192 + w * 960;    // [48][20] bf16

  const int lq = l0 + ln;               // this lane's q-row (swapped ops)
  bf8 qf[2];
  {
    const u16* qp = qbg + hoff + (size_t)lq * HDD + g * 8;
    qf[0] = *(const bf8*)qp;
    qf[1] = *(const bf8*)(qp + 32);
  }

  f32x4 acc1[4] = {}, acc2[4] = {};
  float m1 = -INFINITY, m2 = -INFINITY, sum1 = 0.f, sum2 = 0.f;

  const int vrow = lane;                // V d-row
  const int vx   = (vrow & 3) << 3;
  const u16* vgp = vtg + hoff + (size_t)vrow * SS;
  const u16* kgp = kbg + hoff;
  const u16* Srow = smb + (size_t)lq * SS;
  const float* Arow = am + (b << 10);

  const int S0base = 16 * ((2 * g) & 3) + ln;
  const int S1base = 16 * ((2 * g + 1) & 3) + ln;
  const bool gh = (lane & 32) != 0;     // g >= 2 -> source pk[1]

  const int rbase = 256 * w;

  // prologue: stage V tile 0 (wave-private; same-wave lgkmcnt ordering)
  u16x8 vq[4];
  {
    const u16* vg = vgp + rbase;
    vq[0] = *(const u16x8*)(vg + 0);
    vq[1] = *(const u16x8*)(vg + 8);
    vq[2] = *(const u16x8*)(vg + 16);
    vq[3] = *(const u16x8*)(vg + 24);
#pragma unroll
    for (int c = 0; c < 4; ++c)
      *(u16x8*)&vsw[vrow * 32 + ((8 * c) ^ vx)] = vq[c];
  }

  for (int t = 0; t < 8; ++t) {
    const int r0 = rbase + 32 * t;

    // K A-frags direct from global
    bf8 kf[2][2];
#pragma unroll
    for (int ct = 0; ct < 2; ++ct) {
      const u16* kp = kgp + (size_t)(r0 + 16 * ct + ln) * HDD + g * 8;
      kf[ct][0] = *(const bf8*)kp;
      kf[ct][1] = *(const bf8*)(kp + 32);
    }
    // masks: r = r0+16ct+4g+i, q = lq
    f32x4 amv[2];
    u16x4 smv[2];
#pragma unroll
    for (int ct = 0; ct < 2; ++ct) {
      amv[ct] = *(const f32x4*)&Arow[r0 + 16 * ct + 4 * g];
      smv[ct] = *(const u16x4*)&Srow[r0 + 16 * ct + 4 * g];
    }
    // V B-frags from LDS (tile t, staged last iter)
    bf8 vbf[4];
#pragma unroll
    for (int dt = 0; dt < 4; ++dt)
      vbf[dt] = *(const bf8*)&vsw[(16 * dt + ln) * 32 + 8 * (g ^ (ln & 3))];

    // issue V loads for tile t+1 (latency hidden under compute + TLP)
    if (t < 7) {
      const u16* vg = vgp + r0 + 32;
      vq[0] = *(const u16x8*)(vg + 0);
      vq[1] = *(const u16x8*)(vg + 8);
      vq[2] = *(const u16x8*)(vg + 16);
      vq[3] = *(const u16x8*)(vg + 24);
    }

    __builtin_amdgcn_s_setprio(1);
    // T = mfma(E_window, Q): window 48 rows (KVBLK=32 + 16 q - 1)
    const int W0 = l0 - r0 + 992;
#pragma unroll
    for (int c5 = 0; c5 < 3; ++c5) {
      const int gr = min(W0 + 16 * c5 + ln, 2046);
      const u16* ep = eb + (size_t)gr * HDD + g * 8;
      f32x4 x = {0.f, 0.f, 0.f, 0.f};
      x = __builtin_amdgcn_mfma_f32_16x16x32_bf16(*(const bf8*)ep, qf[0], x, 0, 0, 0);
      x = __builtin_amdgcn_mfma_f32_16x16x32_bf16(*(const bf8*)(ep + 32), qf[1], x, 0, 0, 0);
#pragma unroll
      for (int i = 0; i < 4; ++i)
        Tw[(16 * c5 + 4 * g + i) * 20 + ln] = f2bf(x[i]);
    }
    // QK^T swapped: sc[ct][i] = S[r=16ct+4g+i][q=ln]
    f32x4 sc[2];
#pragma unroll
    for (int ct = 0; ct < 2; ++ct) {
      f32x4 x = {0.f, 0.f, 0.f, 0.f};
      x = __builtin_amdgcn_mfma_f32_16x16x32_bf16(kf[ct][0], qf[0], x, 0, 0, 0);
      x = __builtin_amdgcn_mfma_f32_16x16x32_bf16(kf[ct][1], qf[1], x, 0, 0, 0);
      sc[ct] = x;
    }
    __builtin_amdgcn_s_setprio(0);

    // scores + Toeplitz bias (column-local T gather; e = ln + 31 - r_local)
    float s1r[2][4], s2r[2][4];
#pragma unroll
    for (int ct = 0; ct < 2; ++ct)
#pragma unroll
      for (int i = 0; i < 4; ++i) {
        const int e = ln + 31 - 16 * ct - 4 * g - i;
        const float tb = bf2f(Tw[e * 20 + ln]);
        const float s1 = (sc[ct][i] + tb) * 0.125f + amv[ct][i];
        s1r[ct][i] = s1;
        s2r[ct][i] = s1 * bf2f(smv[ct][i]) + amv[ct][i];
      }

    bf8 pa1, pa2;
    // ---- branch 1: defer-max softmax (R8-validated) ----
    {
      float pmax = s1r[0][0];
#pragma unroll
      for (int ct = 0; ct < 2; ++ct)
#pragma unroll
        for (int i = 0; i < 4; ++i) pmax = fmaxf(pmax, s1r[ct][i]);
      if (!__all(pmax <= m1 + 8.f)) {
        float mx = fmaxf(pmax, __shfl_xor(pmax, 16, 64));
        mx = fmaxf(mx, __shfl_xor(mx, 32, 64));
        const float mn = fmaxf(m1, mx);
        const float scl = __expf(m1 - mn);
        m1 = mn;
        sum1 *= scl;
#pragma unroll
        for (int i = 0; i < 4; ++i) {
          const float s = __shfl(scl, (lane & 48) + 4 * g + i, 64);
#pragma unroll
          for (int dt = 0; dt < 4; ++dt) acc1[dt][i] *= s;
        }
      }
      u32 pk[2][2];
      float rs = 0.f;
#pragma unroll
      for (int ct = 0; ct < 2; ++ct) {
        const float p0 = __expf(s1r[ct][0] - m1);
        const float p1 = __expf(s1r[ct][1] - m1);
        const float p2 = __expf(s1r[ct][2] - m1);
        const float p3 = __expf(s1r[ct][3] - m1);
        rs += (p0 + p1) + (p2 + p3);
        pk[ct][0] = (u32)f2bf(p0) | ((u32)f2bf(p1) << 16);
        pk[ct][1] = (u32)f2bf(p2) | ((u32)f2bf(p3) << 16);
      }
      sum1 += rs;  // per-lane partial; reduced once at the end
      union { u32 u[4]; bf8 v; } f;
      u32 a, bb2;
      a = (u32)__shfl((int)pk[0][0], S0base, 64);
      bb2 = (u32)__shfl((int)pk[1][0], S0base, 64);
      f.u[0] = gh ? bb2 : a;
      a = (u32)__shfl((int)pk[0][1], S0base, 64);
      bb2 = (u32)__shfl((int)pk[1][1], S0base, 64);
      f.u[1] = gh ? bb2 : a;
      a = (u32)__shfl((int)pk[0][0], S1base, 64);
      bb2 = (u32)__shfl((int)pk[1][0], S1base, 64);
      f.u[2] = gh ? bb2 : a;
      a = (u32)__shfl((int)pk[0][1], S1base, 64);
      bb2 = (u32)__shfl((int)pk[1][1], S1base, 64);
      f.u[3] = gh ? bb2 : a;
      pa1 = f.v;
    }
    // ---- branch 2 ----
    {
      float pmax = s2r[0][0];
#pragma unroll
      for (int ct = 0; ct < 2; ++ct)
#pragma unroll
        for (int i = 0; i < 4; ++i) pmax = fmaxf(pmax, s2r[ct][i]);
      if (!__all(pmax <= m2 + 8.f)) {
        float mx = fmaxf(pmax, __shfl_xor(pmax, 16, 64));
        mx = fmaxf(mx, __shfl_xor(mx, 32, 64));
        const float mn = fmaxf(m2, mx);
        const float scl = __expf(m2 - mn);
        m2 = mn;
        sum2 *= scl;
#pragma unroll
        for (int i = 0; i < 4; ++i) {
          const float s = __shfl(scl, (lane & 48) + 4 * g + i, 64);
#pragma unroll
          for (int dt = 0; dt < 4; ++dt) acc2[dt][i] *= s;
        }
      }
      u32 pk[2][2];
      float rs = 0.f;
#pragma unroll
      for (int ct = 0; ct < 2; ++ct) {
        const float p0 = __expf(s2r[ct][0] - m2);
        const float p1 = __expf(s2r[ct][1] - m2);
        const float p2 = __expf(s2r[ct][2] - m2);
        const float p3 = __expf(s2r[ct][3] - m2);
        rs += (p0 + p1) + (p2 + p3);
        pk[ct][0] = (u32)f2bf(p0) | ((u32)f2bf(p1) << 16);
        pk[ct][1] = (u32)f2bf(p2) | ((u32)f2bf(p3) << 16);
      }
      sum2 += rs;
      union { u32 u[4]; bf8 v; } f;
      u32 a, bb2;
      a = (u32)__shfl((int)pk[0][0], S0base, 64);
      bb2 = (u32)__shfl((int)pk[1][0], S0base, 64);
      f.u[0] = gh ? bb2 : a;
      a = (u32)__shfl((int)pk[0][1], S0base, 64);
      bb2 = (u32)__shfl((int)pk[1][1], S0base, 64);
      f.u[1] = gh ? bb2 : a;
      a = (u32)__shfl((int)pk[0][0], S1base, 64);
      bb2 = (u32)__shfl((int)pk[1][0], S1base, 64);
      f.u[2] = gh ? bb2 : a;
      a = (u32)__shfl((int)pk[0][1], S1base, 64);
      bb2 = (u32)__shfl((int)pk[1][1], S1base, 64);
      f.u[3] = gh ? bb2 : a;
      pa2 = f.v;
    }

    // write V tile t+1 into wave-private LDS (vmcnt on vq; no barrier)
    if (t < 7) {
#pragma unroll
      for (int c = 0; c < 4; ++c)
        *(u16x8*)&vsw[vrow * 32 + ((8 * c) ^ vx)] = vq[c];
    }

    // PV: O[q=4g+i][d=16dt+ln], K=32 -> one MFMA per dt per branch
    __builtin_amdgcn_s_setprio(1);
#pragma unroll
    for (int dt = 0; dt < 4; ++dt) {
      acc1[dt] = __builtin_amdgcn_mfma_f32_16x16x32_bf16(pa1, vbf[dt], acc1[dt], 0, 0, 0);
      acc2[dt] = __builtin_amdgcn_mfma_f32_16x16x32_bf16(pa2, vbf[dt], acc2[dt], 0, 0, 0);
    }
    __builtin_amdgcn_s_setprio(0);
  }

  // reduce per-lane partial sums -> row totals (uniform across g-groups)
  sum1 += __shfl_xor(sum1, 16, 64);
  sum1 += __shfl_xor(sum1, 32, 64);
  sum2 += __shfl_xor(sum2, 16, 64);
  sum2 += __shfl_xor(sum2, 32, 64);

  // -------- 4-way split-K merge --------
  __syncthreads();
  float* scr = (float*)smbuf;  // 6336 floats, overlays dead V/T buffers
  if (w > 0) {
    const int base = (w - 1) * 1024;
#pragma unroll
    for (int i = 0; i < 4; ++i) {
      const int row = 4 * g + i;
#pragma unroll
      for (int dt = 0; dt < 4; ++dt) {
        scr[base + row * 64 + dt * 16 + ln] = acc1[dt][i];
        scr[3072 + base + row * 64 + dt * 16 + ln] = acc2[dt][i];
      }
    }
    if (g == 0) {  // one lane per q-row publishes stats (q = ln)
      const int sb = 6144 + (w - 1) * 64 + ln * 4;
      scr[sb + 0] = m1;
      scr[sb + 1] = sum1;
      scr[sb + 2] = m2;
      scr[sb + 3] = sum2;
    }
  }
  __syncthreads();
  if (w == 0) {
    float mw1[3], sw1[3], mw2[3], sw2[3];
#pragma unroll
    for (int j = 0; j < 3; ++j) {
      const int sb = 6144 + j * 64 + ln * 4;
      mw1[j] = scr[sb + 0];
      sw1[j] = scr[sb + 1];
      mw2[j] = scr[sb + 2];
      sw2[j] = scr[sb + 3];
    }
    const float M1 = fmaxf(fmaxf(m1, mw1[0]), fmaxf(mw1[1], mw1[2]));
    const float c10 = __expf(m1 - M1), c11 = __expf(mw1[0] - M1);
    const float c12 = __expf(mw1[1] - M1), c13 = __expf(mw1[2] - M1);
    const float inv1 = 1.f / (sum1 * c10 + sw1[0] * c11 + sw1[1] * c12 + sw1[2] * c13);
    const float a10 = c10 * inv1, a11 = c11 * inv1, a12 = c12 * inv1, a13 = c13 * inv1;
    const float M2 = fmaxf(fmaxf(m2, mw2[0]), fmaxf(mw2[1], mw2[2]));
    const float c20 = __expf(m2 - M2), c21 = __expf(mw2[0] - M2);
    const float c22 = __expf(mw2[1] - M2), c23 = __expf(mw2[2] - M2);
    const float inv2 = 1.f / (sum2 * c20 + sw2[0] * c21 + sw2[1] * c22 + sw2[2] * c23);
    const float a20 = c20 * inv2, a21 = c21 * inv2, a22 = c22 * inv2, a23 = c23 * inv2;
#pragma unroll
    for (int i = 0; i < 4; ++i) {
      const int src = (lane & 48) + 4 * g + i;
      const float b10 = __shfl(a10, src, 64), b11 = __shfl(a11, src, 64);
      const float b12 = __shfl(a12, src, 64), b13 = __shfl(a13, src, 64);
      const float b20 = __shfl(a20, src, 64), b21 = __shfl(a21, src, 64);
      const float b22 = __shfl(a22, src, 64), b23 = __shfl(a23, src, 64);
      const int row = 4 * g + i;
      const int lg = l0 + row;
      const float se = selp[(b << 10) + lg];
#pragma unroll
      for (int dt = 0; dt < 4; ++dt) {
        const int off = row * 64 + dt * 16 + ln;
        const float o1 = acc1[dt][i] * b10 + scr[off] * b11 +
                         scr[1024 + off] * b12 + scr[2048 + off] * b13;
        const float o2 = acc2[dt][i] * b20 + scr[3072 + off] * b21 +
                         scr[4096 + off] * b22 + scr[5120 + off] * b23;
        out[((size_t)((b << 10) + lg)) * HIDD + h * HDD + dt * 16 + ln] =
            se * o2 + (1.f - se) * o1;
      }
    }
  }
}

extern "C" void kernel_launch(void* const* d_in, const int* in_sizes, int n_in,
                              void* d_out, int out_size, void* d_ws, size_t ws_size,
                              hipStream_t stream) {
  const float* hidden = (const float*)d_in[0];
  const float* am     = (const float*)d_in[1];
  const float* smask  = (const float*)d_in[2];
  const float* selp   = (const float*)d_in[3];
  const float* Wq     = (const float*)d_in[4];
  const float* bq     = (const float*)d_in[5];
  const float* Wk     = (const float*)d_in[6];
  const float* bk     = (const float*)d_in[7];
  const float* Wv     = (const float*)d_in[8];
  const float* bv     = (const float*)d_in[9];
  const float* demb   = (const float*)d_in[10];
  float* out = (float*)d_out;

  u16* wsp = (u16*)d_ws;
  const size_t NEL = (size_t)BB * NHH * SS * HDD;  // 1572864
  u16* Xb  = wsp;
  u16* Wt  = Xb + (size_t)2048 * HIDD;
  u16* qbw = Wt + (size_t)3 * HIDD * HIDD;
  u16* kbw = qbw + NEL;
  u16* vtw = kbw + NEL;
  u16* ebw = vtw + NEL;
  u16* smb = ebw + (size_t)2047 * HDD;

  xconv_kernel<<<768, 256, 0, stream>>>(hidden, Xb);
  dim3 gw(HIDD / 64, HIDD / 64, 3);
  wtconv_kernel<<<gw, 256, 0, stream>>>(Wq, Wk, Wv, Wt);
  econv_kernel<<<64, 256, 0, stream>>>(demb, ebw);
  sconv_kernel<<<512, 256, 0, stream>>>(smask, smb);

  dim3 g1(18, 32);
  qkv_mfma_kernel<<<g1, 256, 0, stream>>>(Xb, Wt, bq, bk, bv, qbw, kbw, vtw);

  attn_kernel<<<1536, 256, 0, stream>>>(qbw, kbw, vtw, ebw, am, smb, selp, out);
}

// Round 11
// 178.587 us; speedup vs baseline: 2.6046x; 1.6834x over previous
//
#include <hip/hip_runtime.h>
#include <hip/hip_bf16.h>
#include <math.h>

#define BB   2
#define SS   1024
#define HIDD 768
#define NHH  12
#define HDD  64

typedef float f32x4 __attribute__((ext_vector_type(4)));
typedef short bf8   __attribute__((ext_vector_type(8)));   // 8 bf16 (bit pattern)
typedef unsigned short u16;
typedef unsigned int u32;
typedef u16 u16x8 __attribute__((ext_vector_type(8)));
typedef u16 u16x4 __attribute__((ext_vector_type(4)));

__device__ __forceinline__ u16 f2bf(float x) {  // RNE f32->bf16
  unsigned int u = __float_as_uint(x);
  u += 0x7fffu + ((u >> 16) & 1u);
  return (u16)(u >> 16);
}
__device__ __forceinline__ float bf2f(u16 x) {
  return __uint_as_float(((u32)x) << 16);
}

__device__ __forceinline__ bf8 ldfrag(const u16* t, int row, int kc) {
  return *(const bf8*)&t[row * 64 + (kc ^ ((row & 7) << 3))];
}

// ---------------------------------------------------------------------------
// Prep kernels (unchanged).
// ---------------------------------------------------------------------------
__global__ __launch_bounds__(256) void xconv_kernel(const float* __restrict__ X,
                                                    u16* __restrict__ Xb) {
  int i = (blockIdx.x * 256 + threadIdx.x) * 8;
  float4 a = *(const float4*)&X[i];
  float4 b = *(const float4*)&X[i + 4];
  u16x8 o;
  o[0] = f2bf(a.x); o[1] = f2bf(a.y); o[2] = f2bf(a.z); o[3] = f2bf(a.w);
  o[4] = f2bf(b.x); o[5] = f2bf(b.y); o[6] = f2bf(b.z); o[7] = f2bf(b.w);
  *(u16x8*)&Xb[i] = o;
}

__global__ __launch_bounds__(256) void wtconv_kernel(
    const float* __restrict__ Wq, const float* __restrict__ Wk,
    const float* __restrict__ Wv, u16* __restrict__ Wt) {
  const int zi = blockIdx.z;
  const float* __restrict__ W = (zi == 0) ? Wq : (zi == 1 ? Wk : Wv);
  const int n0 = blockIdx.x * 64;
  const int k0 = blockIdx.y * 64;
  __shared__ float t[64][65];
  const int tid = threadIdx.x;
  {
    const int kl = tid >> 4;
    const int nl = (tid & 15) * 4;
#pragma unroll
    for (int p = 0; p < 4; ++p) {
      float4 v = *(const float4*)&W[(size_t)(k0 + kl + 16 * p) * HIDD + n0 + nl];
      t[kl + 16 * p][nl + 0] = v.x;
      t[kl + 16 * p][nl + 1] = v.y;
      t[kl + 16 * p][nl + 2] = v.z;
      t[kl + 16 * p][nl + 3] = v.w;
    }
  }
  __syncthreads();
  {
    const int nl = tid >> 4;
    const int cl = (tid & 15) * 4;
#pragma unroll
    for (int p = 0; p < 4; ++p) {
      const int n = nl + 16 * p;
      u16x4 o;
      o[0] = f2bf(t[cl + 0][n]);
      o[1] = f2bf(t[cl + 1][n]);
      o[2] = f2bf(t[cl + 2][n]);
      o[3] = f2bf(t[cl + 3][n]);
      *(u16x4*)&Wt[(size_t)(zi * HIDD + n0 + n) * HIDD + k0 + cl] = o;
    }
  }
}

__global__ __launch_bounds__(256) void econv_kernel(const float* __restrict__ demb,
                                                    u16* __restrict__ eb) {
  int i = (blockIdx.x * 256 + threadIdx.x) * 8;
  if (i < 2047 * HDD) {
    float4 a = *(const float4*)&demb[i];
    float4 b = *(const float4*)&demb[i + 4];
    u16x8 o;
    o[0] = f2bf(a.x); o[1] = f2bf(a.y); o[2] = f2bf(a.z); o[3] = f2bf(a.w);
    o[4] = f2bf(b.x); o[5] = f2bf(b.y); o[6] = f2bf(b.z); o[7] = f2bf(b.w);
    *(u16x8*)&eb[i] = o;
  }
}

__global__ __launch_bounds__(256) void sconv_kernel(const float* __restrict__ sm,
                                                    u16* __restrict__ smb) {
  int i = (blockIdx.x * 256 + threadIdx.x) * 8;
  float4 a = *(const float4*)&sm[i];
  float4 b = *(const float4*)&sm[i + 4];
  u16x8 o;
  o[0] = f2bf(a.x); o[1] = f2bf(a.y); o[2] = f2bf(a.z); o[3] = f2bf(a.w);
  o[4] = f2bf(b.x); o[5] = f2bf(b.y); o[6] = f2bf(b.z); o[7] = f2bf(b.w);
  *(u16x8*)&smb[i] = o;
}

// ---------------------------------------------------------------------------
// Fused QKV MFMA GEMM (unchanged).
// ---------------------------------------------------------------------------
__global__ __launch_bounds__(256) void qkv_mfma_kernel(
    const u16* __restrict__ Xb, const u16* __restrict__ Wt,
    const float* __restrict__ bq, const float* __restrict__ bk,
    const float* __restrict__ bv,
    u16* __restrict__ qb, u16* __restrict__ kb, u16* __restrict__ vt) {
  const int bn = blockIdx.x;
  const int bm = blockIdx.y;
  const int zi = bn / 6;

  __shared__ u16 As[64 * 64];
  __shared__ u16 Bs[128 * 64];

  const int tid  = threadIdx.x;
  const int lane = tid & 63;
  const int w    = tid >> 6;
  const int g    = lane >> 4;
  const int ln   = lane & 15;
  const int wm   = (w >> 1) * 32;
  const int wn   = (w & 1) * 64;

  f32x4 acc[2][4] = {};

  const int srow = tid >> 3;
  const int scol = (tid & 7) * 8;
  const u16* Ag = Xb + (size_t)(bm * 64 + srow) * HIDD + scol;
  const u16* Bg = Wt + (size_t)(bn * 128 + srow) * HIDD + scol;

  for (int k0 = 0; k0 < HIDD; k0 += 64) {
    if (k0) __syncthreads();
#pragma unroll
    for (int p = 0; p < 2; ++p) {
      const int r = srow + 32 * p;
      const int sw = (r & 7) << 3;
      *(u16x8*)&As[r * 64 + (scol ^ sw)] =
          *(const u16x8*)&Ag[(size_t)(32 * p) * HIDD + k0];
    }
#pragma unroll
    for (int p = 0; p < 4; ++p) {
      const int r = srow + 32 * p;
      const int sw = (r & 7) << 3;
      *(u16x8*)&Bs[r * 64 + (scol ^ sw)] =
          *(const u16x8*)&Bg[(size_t)(32 * p) * HIDD + k0];
    }
    __syncthreads();

    bf8 af[2][2], bfr[4][2];
#pragma unroll
    for (int f = 0; f < 2; ++f)
#pragma unroll
      for (int kk = 0; kk < 2; ++kk)
        af[f][kk] = ldfrag(As, wm + 16 * f + ln, kk * 32 + g * 8);
#pragma unroll
    for (int f = 0; f < 4; ++f)
#pragma unroll
      for (int kk = 0; kk < 2; ++kk)
        bfr[f][kk] = ldfrag(Bs, wn + 16 * f + ln, kk * 32 + g * 8);
    if (zi < 2) {
#pragma unroll
      for (int mf = 0; mf < 2; ++mf)
#pragma unroll
        for (int nf = 0; nf < 4; ++nf)
#pragma unroll
          for (int kk = 0; kk < 2; ++kk)
            acc[mf][nf] = __builtin_amdgcn_mfma_f32_16x16x32_bf16(
                bfr[nf][kk], af[mf][kk], acc[mf][nf], 0, 0, 0);
    } else {
#pragma unroll
      for (int mf = 0; mf < 2; ++mf)
#pragma unroll
        for (int nf = 0; nf < 4; ++nf)
#pragma unroll
          for (int kk = 0; kk < 2; ++kk)
            acc[mf][nf] = __builtin_amdgcn_mfma_f32_16x16x32_bf16(
                af[mf][kk], bfr[nf][kk], acc[mf][nf], 0, 0, 0);
    }
  }

  const int mrow  = bm * 64 + wm;
  const int nbase = (bn % 6) * 128 + wn;
  const int h     = nbase >> 6;

  if (zi < 2) {
    const float* __restrict__ bias = zi ? bk : bq;
    u16* __restrict__ outp = zi ? kb : qb;
#pragma unroll
    for (int nf = 0; nf < 4; ++nf) {
      const int d0 = 16 * nf + 4 * g;
      float4 bi = *(const float4*)&bias[nbase + d0];
#pragma unroll
      for (int mf = 0; mf < 2; ++mf) {
        const int m = mrow + 16 * mf + ln;
        const int b = m >> 10, s = m & 1023;
        u16x4 o;
        o[0] = f2bf(acc[mf][nf][0] + bi.x);
        o[1] = f2bf(acc[mf][nf][1] + bi.y);
        o[2] = f2bf(acc[mf][nf][2] + bi.z);
        o[3] = f2bf(acc[mf][nf][3] + bi.w);
        *(u16x4*)&outp[(((size_t)(b * NHH + h)) * SS + s) * HDD + d0] = o;
      }
    }
  } else {
#pragma unroll
    for (int nf = 0; nf < 4; ++nf) {
      const int d = 16 * nf + ln;
      const float bi = bv[nbase + d];
#pragma unroll
      for (int mf = 0; mf < 2; ++mf) {
        const int m = mrow + 16 * mf + 4 * g;
        const int b = m >> 10, s = m & 1023;
        u16x4 o;
        o[0] = f2bf(acc[mf][nf][0] + bi);
        o[1] = f2bf(acc[mf][nf][1] + bi);
        o[2] = f2bf(acc[mf][nf][2] + bi);
        o[3] = f2bf(acc[mf][nf][3] + bi);
        *(u16x4*)&vt[(((size_t)(b * NHH + h)) * HDD + d) * SS + s] = o;
      }
    }
  }
}

// ---------------------------------------------------------------------------
// attn v11 = v10 with the VGPR cap fixed: __launch_bounds__(256, 4)
// (cap 128 >= natural ~100; R10's (256,6) forced 40 VGPR -> 1.2GB spill).
// QBLK=16, grid 1536, 4 waves split-K x4, KVBLK=32, barrier-free loop.
// ---------------------------------------------------------------------------
__global__ __launch_bounds__(256, 4) void attn_kernel(
    const u16* __restrict__ qbg,     // [B*NH][S][64] bf16
    const u16* __restrict__ kbg,     // [B*NH][S][64] bf16
    const u16* __restrict__ vtg,     // [B*NH][64][S] bf16
    const u16* __restrict__ eb,      // [2047][64] bf16
    const float* __restrict__ am,    // [B][S]
    const u16* __restrict__ smb,     // [S][S] bf16
    const float* __restrict__ selp,  // [B][S]
    float* __restrict__ out) {       // [B][S][768]
  // XCD-bijective swizzle: all 64 q-tiles of one (b,h) share bid&7.
  const int bid  = blockIdx.x;          // 0..1535
  const int xcd  = bid & 7;
  const int idx  = bid >> 3;            // 0..191
  const int inner = idx & 63;           // q-tile
  const int grp  = idx >> 6;            // 0..2
  const int hg   = grp * 8 + xcd;       // 0..23
  const int h    = hg % NHH;
  const int b    = hg / NHH;
  const int l0   = inner * 16;

  const int bh = b * NHH + h;
  const size_t hoff = (size_t)bh * SS * HDD;

  // 25.6KB: V 4x[64][32] (8192 u16) | T 4x[48][20] (3840 u16) | merge overlay
  __shared__ __align__(16) u16 smbuf[12800];

  const int tid  = threadIdx.x;
  const int lane = tid & 63;
  const int w    = tid >> 6;   // 0..3 = r-quarter
  const int g    = lane >> 4;
  const int ln   = lane & 15;

  u16* vsw = smbuf + w * 2048;          // [64 d][32 r] swizzled
  u16* Tw  = smbuf + 8192 + w * 960;    // [48][20] bf16

  const int lq = l0 + ln;               // this lane's q-row (swapped ops)
  bf8 qf[2];
  {
    const u16* qp = qbg + hoff + (size_t)lq * HDD + g * 8;
    qf[0] = *(const bf8*)qp;
    qf[1] = *(const bf8*)(qp + 32);
  }

  f32x4 acc1[4] = {}, acc2[4] = {};
  float m1 = -INFINITY, m2 = -INFINITY, sum1 = 0.f, sum2 = 0.f;

  const int vrow = lane;                // V d-row
  const int vx   = (vrow & 3) << 3;
  const u16* vgp = vtg + hoff + (size_t)vrow * SS;
  const u16* kgp = kbg + hoff;
  const u16* Srow = smb + (size_t)lq * SS;
  const float* Arow = am + (b << 10);

  const int S0base = 16 * ((2 * g) & 3) + ln;
  const int S1base = 16 * ((2 * g + 1) & 3) + ln;
  const bool gh = (lane & 32) != 0;     // g >= 2 -> source pk[1]

  const int rbase = 256 * w;

  // prologue: stage V tile 0 (wave-private; same-wave lgkmcnt ordering)
  u16x8 vq[4];
  {
    const u16* vg = vgp + rbase;
    vq[0] = *(const u16x8*)(vg + 0);
    vq[1] = *(const u16x8*)(vg + 8);
    vq[2] = *(const u16x8*)(vg + 16);
    vq[3] = *(const u16x8*)(vg + 24);
#pragma unroll
    for (int c = 0; c < 4; ++c)
      *(u16x8*)&vsw[vrow * 32 + ((8 * c) ^ vx)] = vq[c];
  }

  for (int t = 0; t < 8; ++t) {
    const int r0 = rbase + 32 * t;

    // K A-frags direct from global
    bf8 kf[2][2];
#pragma unroll
    for (int ct = 0; ct < 2; ++ct) {
      const u16* kp = kgp + (size_t)(r0 + 16 * ct + ln) * HDD + g * 8;
      kf[ct][0] = *(const bf8*)kp;
      kf[ct][1] = *(const bf8*)(kp + 32);
    }
    // masks: r = r0+16ct+4g+i, q = lq
    f32x4 amv[2];
    u16x4 smv[2];
#pragma unroll
    for (int ct = 0; ct < 2; ++ct) {
      amv[ct] = *(const f32x4*)&Arow[r0 + 16 * ct + 4 * g];
      smv[ct] = *(const u16x4*)&Srow[r0 + 16 * ct + 4 * g];
    }
    // V B-frags from LDS (tile t, staged last iter)
    bf8 vbf[4];
#pragma unroll
    for (int dt = 0; dt < 4; ++dt)
      vbf[dt] = *(const bf8*)&vsw[(16 * dt + ln) * 32 + 8 * (g ^ (ln & 3))];

    // issue V loads for tile t+1 (latency hidden under compute + TLP)
    if (t < 7) {
      const u16* vg = vgp + r0 + 32;
      vq[0] = *(const u16x8*)(vg + 0);
      vq[1] = *(const u16x8*)(vg + 8);
      vq[2] = *(const u16x8*)(vg + 16);
      vq[3] = *(const u16x8*)(vg + 24);
    }

    __builtin_amdgcn_s_setprio(1);
    // T = mfma(E_window, Q): window 48 rows (KVBLK=32 + 16 q - 1)
    const int W0 = l0 - r0 + 992;
#pragma unroll
    for (int c5 = 0; c5 < 3; ++c5) {
      const int gr = min(W0 + 16 * c5 + ln, 2046);
      const u16* ep = eb + (size_t)gr * HDD + g * 8;
      f32x4 x = {0.f, 0.f, 0.f, 0.f};
      x = __builtin_amdgcn_mfma_f32_16x16x32_bf16(*(const bf8*)ep, qf[0], x, 0, 0, 0);
      x = __builtin_amdgcn_mfma_f32_16x16x32_bf16(*(const bf8*)(ep + 32), qf[1], x, 0, 0, 0);
#pragma unroll
      for (int i = 0; i < 4; ++i)
        Tw[(16 * c5 + 4 * g + i) * 20 + ln] = f2bf(x[i]);
    }
    // QK^T swapped: sc[ct][i] = S[r=16ct+4g+i][q=ln]
    f32x4 sc[2];
#pragma unroll
    for (int ct = 0; ct < 2; ++ct) {
      f32x4 x = {0.f, 0.f, 0.f, 0.f};
      x = __builtin_amdgcn_mfma_f32_16x16x32_bf16(kf[ct][0], qf[0], x, 0, 0, 0);
      x = __builtin_amdgcn_mfma_f32_16x16x32_bf16(kf[ct][1], qf[1], x, 0, 0, 0);
      sc[ct] = x;
    }
    __builtin_amdgcn_s_setprio(0);

    // scores + Toeplitz bias (column-local T gather; e = ln + 31 - r_local)
    float s1r[2][4], s2r[2][4];
#pragma unroll
    for (int ct = 0; ct < 2; ++ct)
#pragma unroll
      for (int i = 0; i < 4; ++i) {
        const int e = ln + 31 - 16 * ct - 4 * g - i;
        const float tb = bf2f(Tw[e * 20 + ln]);
        const float s1 = (sc[ct][i] + tb) * 0.125f + amv[ct][i];
        s1r[ct][i] = s1;
        s2r[ct][i] = s1 * bf2f(smv[ct][i]) + amv[ct][i];
      }

    bf8 pa1, pa2;
    // ---- branch 1: defer-max softmax (R8-validated) ----
    {
      float pmax = s1r[0][0];
#pragma unroll
      for (int ct = 0; ct < 2; ++ct)
#pragma unroll
        for (int i = 0; i < 4; ++i) pmax = fmaxf(pmax, s1r[ct][i]);
      if (!__all(pmax <= m1 + 8.f)) {
        float mx = fmaxf(pmax, __shfl_xor(pmax, 16, 64));
        mx = fmaxf(mx, __shfl_xor(mx, 32, 64));
        const float mn = fmaxf(m1, mx);
        const float scl = __expf(m1 - mn);
        m1 = mn;
        sum1 *= scl;
#pragma unroll
        for (int i = 0; i < 4; ++i) {
          const float s = __shfl(scl, (lane & 48) + 4 * g + i, 64);
#pragma unroll
          for (int dt = 0; dt < 4; ++dt) acc1[dt][i] *= s;
        }
      }
      u32 pk[2][2];
      float rs = 0.f;
#pragma unroll
      for (int ct = 0; ct < 2; ++ct) {
        const float p0 = __expf(s1r[ct][0] - m1);
        const float p1 = __expf(s1r[ct][1] - m1);
        const float p2 = __expf(s1r[ct][2] - m1);
        const float p3 = __expf(s1r[ct][3] - m1);
        rs += (p0 + p1) + (p2 + p3);
        pk[ct][0] = (u32)f2bf(p0) | ((u32)f2bf(p1) << 16);
        pk[ct][1] = (u32)f2bf(p2) | ((u32)f2bf(p3) << 16);
      }
      sum1 += rs;  // per-lane partial; reduced once at the end
      union { u32 u[4]; bf8 v; } f;
      u32 a, bb2;
      a = (u32)__shfl((int)pk[0][0], S0base, 64);
      bb2 = (u32)__shfl((int)pk[1][0], S0base, 64);
      f.u[0] = gh ? bb2 : a;
      a = (u32)__shfl((int)pk[0][1], S0base, 64);
      bb2 = (u32)__shfl((int)pk[1][1], S0base, 64);
      f.u[1] = gh ? bb2 : a;
      a = (u32)__shfl((int)pk[0][0], S1base, 64);
      bb2 = (u32)__shfl((int)pk[1][0], S1base, 64);
      f.u[2] = gh ? bb2 : a;
      a = (u32)__shfl((int)pk[0][1], S1base, 64);
      bb2 = (u32)__shfl((int)pk[1][1], S1base, 64);
      f.u[3] = gh ? bb2 : a;
      pa1 = f.v;
    }
    // ---- branch 2 ----
    {
      float pmax = s2r[0][0];
#pragma unroll
      for (int ct = 0; ct < 2; ++ct)
#pragma unroll
        for (int i = 0; i < 4; ++i) pmax = fmaxf(pmax, s2r[ct][i]);
      if (!__all(pmax <= m2 + 8.f)) {
        float mx = fmaxf(pmax, __shfl_xor(pmax, 16, 64));
        mx = fmaxf(mx, __shfl_xor(mx, 32, 64));
        const float mn = fmaxf(m2, mx);
        const float scl = __expf(m2 - mn);
        m2 = mn;
        sum2 *= scl;
#pragma unroll
        for (int i = 0; i < 4; ++i) {
          const float s = __shfl(scl, (lane & 48) + 4 * g + i, 64);
#pragma unroll
          for (int dt = 0; dt < 4; ++dt) acc2[dt][i] *= s;
        }
      }
      u32 pk[2][2];
      float rs = 0.f;
#pragma unroll
      for (int ct = 0; ct < 2; ++ct) {
        const float p0 = __expf(s2r[ct][0] - m2);
        const float p1 = __expf(s2r[ct][1] - m2);
        const float p2 = __expf(s2r[ct][2] - m2);
        const float p3 = __expf(s2r[ct][3] - m2);
        rs += (p0 + p1) + (p2 + p3);
        pk[ct][0] = (u32)f2bf(p0) | ((u32)f2bf(p1) << 16);
        pk[ct][1] = (u32)f2bf(p2) | ((u32)f2bf(p3) << 16);
      }
      sum2 += rs;
      union { u32 u[4]; bf8 v; } f;
      u32 a, bb2;
      a = (u32)__shfl((int)pk[0][0], S0base, 64);
      bb2 = (u32)__shfl((int)pk[1][0], S0base, 64);
      f.u[0] = gh ? bb2 : a;
      a = (u32)__shfl((int)pk[0][1], S0base, 64);
      bb2 = (u32)__shfl((int)pk[1][1], S0base, 64);
      f.u[1] = gh ? bb2 : a;
      a = (u32)__shfl((int)pk[0][0], S1base, 64);
      bb2 = (u32)__shfl((int)pk[1][0], S1base, 64);
      f.u[2] = gh ? bb2 : a;
      a = (u32)__shfl((int)pk[0][1], S1base, 64);
      bb2 = (u32)__shfl((int)pk[1][1], S1base, 64);
      f.u[3] = gh ? bb2 : a;
      pa2 = f.v;
    }

    // write V tile t+1 into wave-private LDS (vmcnt on vq; no barrier)
    if (t < 7) {
#pragma unroll
      for (int c = 0; c < 4; ++c)
        *(u16x8*)&vsw[vrow * 32 + ((8 * c) ^ vx)] = vq[c];
    }

    // PV: O[q=4g+i][d=16dt+ln], K=32 -> one MFMA per dt per branch
    __builtin_amdgcn_s_setprio(1);
#pragma unroll
    for (int dt = 0; dt < 4; ++dt) {
      acc1[dt] = __builtin_amdgcn_mfma_f32_16x16x32_bf16(pa1, vbf[dt], acc1[dt], 0, 0, 0);
      acc2[dt] = __builtin_amdgcn_mfma_f32_16x16x32_bf16(pa2, vbf[dt], acc2[dt], 0, 0, 0);
    }
    __builtin_amdgcn_s_setprio(0);
  }

  // reduce per-lane partial sums -> row totals (uniform across g-groups)
  sum1 += __shfl_xor(sum1, 16, 64);
  sum1 += __shfl_xor(sum1, 32, 64);
  sum2 += __shfl_xor(sum2, 16, 64);
  sum2 += __shfl_xor(sum2, 32, 64);

  // -------- 4-way split-K merge --------
  __syncthreads();
  float* scr = (float*)smbuf;  // 6336 floats, overlays dead V/T buffers
  if (w > 0) {
    const int base = (w - 1) * 1024;
#pragma unroll
    for (int i = 0; i < 4; ++i) {
      const int row = 4 * g + i;
#pragma unroll
      for (int dt = 0; dt < 4; ++dt) {
        scr[base + row * 64 + dt * 16 + ln] = acc1[dt][i];
        scr[3072 + base + row * 64 + dt * 16 + ln] = acc2[dt][i];
      }
    }
    if (g == 0) {  // one lane per q-row publishes stats (q = ln)
      const int sb = 6144 + (w - 1) * 64 + ln * 4;
      scr[sb + 0] = m1;
      scr[sb + 1] = sum1;
      scr[sb + 2] = m2;
      scr[sb + 3] = sum2;
    }
  }
  __syncthreads();
  if (w == 0) {
    float mw1[3], sw1[3], mw2[3], sw2[3];
#pragma unroll
    for (int j = 0; j < 3; ++j) {
      const int sb = 6144 + j * 64 + ln * 4;
      mw1[j] = scr[sb + 0];
      sw1[j] = scr[sb + 1];
      mw2[j] = scr[sb + 2];
      sw2[j] = scr[sb + 3];
    }
    const float M1 = fmaxf(fmaxf(m1, mw1[0]), fmaxf(mw1[1], mw1[2]));
    const float c10 = __expf(m1 - M1), c11 = __expf(mw1[0] - M1);
    const float c12 = __expf(mw1[1] - M1), c13 = __expf(mw1[2] - M1);
    const float inv1 = 1.f / (sum1 * c10 + sw1[0] * c11 + sw1[1] * c12 + sw1[2] * c13);
    const float a10 = c10 * inv1, a11 = c11 * inv1, a12 = c12 * inv1, a13 = c13 * inv1;
    const float M2 = fmaxf(fmaxf(m2, mw2[0]), fmaxf(mw2[1], mw2[2]));
    const float c20 = __expf(m2 - M2), c21 = __expf(mw2[0] - M2);
    const float c22 = __expf(mw2[1] - M2), c23 = __expf(mw2[2] - M2);
    const float inv2 = 1.f / (sum2 * c20 + sw2[0] * c21 + sw2[1] * c22 + sw2[2] * c23);
    const float a20 = c20 * inv2, a21 = c21 * inv2, a22 = c22 * inv2, a23 = c23 * inv2;
#pragma unroll
    for (int i = 0; i < 4; ++i) {
      const int src = (lane & 48) + 4 * g + i;
      const float b10 = __shfl(a10, src, 64), b11 = __shfl(a11, src, 64);
      const float b12 = __shfl(a12, src, 64), b13 = __shfl(a13, src, 64);
      const float b20 = __shfl(a20, src, 64), b21 = __shfl(a21, src, 64);
      const float b22 = __shfl(a22, src, 64), b23 = __shfl(a23, src, 64);
      const int row = 4 * g + i;
      const int lg = l0 + row;
      const float se = selp[(b << 10) + lg];
#pragma unroll
      for (int dt = 0; dt < 4; ++dt) {
        const int off = row * 64 + dt * 16 + ln;
        const float o1 = acc1[dt][i] * b10 + scr[off] * b11 +
                         scr[1024 + off] * b12 + scr[2048 + off] * b13;
        const float o2 = acc2[dt][i] * b20 + scr[3072 + off] * b21 +
                         scr[4096 + off] * b22 + scr[5120 + off] * b23;
        out[((size_t)((b << 10) + lg)) * HIDD + h * HDD + dt * 16 + ln] =
            se * o2 + (1.f - se) * o1;
      }
    }
  }
}

extern "C" void kernel_launch(void* const* d_in, const int* in_sizes, int n_in,
                              void* d_out, int out_size, void* d_ws, size_t ws_size,
                              hipStream_t stream) {
  const float* hidden = (const float*)d_in[0];
  const float* am     = (const float*)d_in[1];
  const float* smask  = (const float*)d_in[2];
  const float* selp   = (const float*)d_in[3];
  const float* Wq     = (const float*)d_in[4];
  const float* bq     = (const float*)d_in[5];
  const float* Wk     = (const float*)d_in[6];
  const float* bk     = (const float*)d_in[7];
  const float* Wv     = (const float*)d_in[8];
  const float* bv     = (const float*)d_in[9];
  const float* demb   = (const float*)d_in[10];
  float* out = (float*)d_out;

  u16* wsp = (u16*)d_ws;
  const size_t NEL = (size_t)BB * NHH * SS * HDD;  // 1572864
  u16* Xb  = wsp;
  u16* Wt  = Xb + (size_t)2048 * HIDD;
  u16* qbw = Wt + (size_t)3 * HIDD * HIDD;
  u16* kbw = qbw + NEL;
  u16* vtw = kbw + NEL;
  u16* ebw = vtw + NEL;
  u16* smb = ebw + (size_t)2047 * HDD;

  xconv_kernel<<<768, 256, 0, stream>>>(hidden, Xb);
  dim3 gw(HIDD / 64, HIDD / 64, 3);
  wtconv_kernel<<<gw, 256, 0, stream>>>(Wq, Wk, Wv, Wt);
  econv_kernel<<<64, 256, 0, stream>>>(demb, ebw);
  sconv_kernel<<<512, 256, 0, stream>>>(smask, smb);

  dim3 g1(18, 32);
  qkv_mfma_kernel<<<g1, 256, 0, stream>>>(Xb, Wt, bq, bk, bv, qbw, kbw, vtw);

  attn_kernel<<<1536, 256, 0, stream>>>(qbw, kbw, vtw, ebw, am, smb, selp, out);
}